// Round 11
// baseline (603.580 us; speedup 1.0000x reference)
//
#include <hip/hip_runtime.h>
#include <hip/hip_bf16.h>
#include <math.h>

#define LEAKY 0.01f
#define SCAN_BLOCK 256
#define SCAN_ITEMS 4
#define SCAN_TILE (SCAN_BLOCK * SCAN_ITEMS)  // 1024 items per block

struct __align__(8) Bf4 { __hip_bfloat16 a, b, c, d; };

// prep: degree histogram WITH returned rank (returning atomic lives in its
// own streaming kernel, overlapped across the grid) fused with the bf16
// conversion of concat(ue, ee).
__global__ void prep(const int* __restrict__ row, int E,
                     int* __restrict__ deg, int* __restrict__ rank,
                     const float4* __restrict__ ue, const float4* __restrict__ ee,
                     __hip_bfloat16* __restrict__ a0b, int nu4, int ntot4) {
    int i = blockIdx.x * blockDim.x + threadIdx.x;
    if (i < E) rank[i] = atomicAdd(&deg[row[i]], 1);
    if (i < ntot4) {
        float4 v = (i < nu4) ? ue[i] : ee[i - nu4];
        Bf4 q = {__float2bfloat16(v.x), __float2bfloat16(v.y),
                 __float2bfloat16(v.z), __float2bfloat16(v.w)};
        *(Bf4*)&a0b[(size_t)i * 4] = q;
    }
}

// ---- scan of deg[N] -> row_ptr[N+1], 2 dispatches ----
__global__ __launch_bounds__(SCAN_BLOCK) void scan_phase1(
    const int* __restrict__ deg, int* __restrict__ blocksum, int N) {
    __shared__ int red[SCAN_BLOCK];
    int b = blockIdx.x, t = threadIdx.x;
    int base = b * SCAN_TILE + t * SCAN_ITEMS;
    int s = 0;
#pragma unroll
    for (int j = 0; j < SCAN_ITEMS; j++) {
        int i = base + j;
        if (i < N) s += deg[i];
    }
    red[t] = s;
    __syncthreads();
    for (int off = SCAN_BLOCK / 2; off > 0; off >>= 1) {
        if (t < off) red[t] += red[t + off];
        __syncthreads();
    }
    if (t == 0) blocksum[b] = red[0];
}

// fused phase2+phase3: every block recomputes its own offset from blocksum
// (G<=1024 ints, L2-broadcast, ~free). row_ptr[N] by thread i==N-1.
__global__ __launch_bounds__(SCAN_BLOCK) void scan_phase23(
    const int* __restrict__ deg, const int* __restrict__ blocksum,
    int* __restrict__ row_ptr, int N) {
    __shared__ int red[SCAN_BLOCK];
    __shared__ int boff_s;
    int b = blockIdx.x, t = threadIdx.x;
    int part = 0;
    for (int j = t; j < b; j += SCAN_BLOCK) part += blocksum[j];
    red[t] = part;
    __syncthreads();
    for (int off = SCAN_BLOCK / 2; off > 0; off >>= 1) {
        if (t < off) red[t] += red[t + off];
        __syncthreads();
    }
    if (t == 0) boff_s = red[0];
    __syncthreads();
    int base = b * SCAN_TILE + t * SCAN_ITEMS;
    int v[SCAN_ITEMS];
    int s = 0;
#pragma unroll
    for (int j = 0; j < SCAN_ITEMS; j++) {
        int i = base + j;
        v[j] = (i < N) ? deg[i] : 0;
        s += v[j];
    }
    red[t] = s;
    __syncthreads();
    for (int off = 1; off < SCAN_BLOCK; off <<= 1) {
        int x = (t >= off) ? red[t - off] : 0;
        __syncthreads();
        red[t] += x;
        __syncthreads();
    }
    int run = boff_s + ((t == 0) ? 0 : red[t - 1]);
#pragma unroll
    for (int j = 0; j < SCAN_ITEMS; j++) {
        int i = base + j;
        if (i < N) {
            row_ptr[i] = run;
            run += v[j];
            if (i == N - 1) row_ptr[N] = run;
        }
    }
}
// ----------------------------------------------------------------------

// atomic-free CSR fill using precomputed ranks (plain store).
__global__ void fill_csr(const int* __restrict__ row, const int* __restrict__ col,
                         const float* __restrict__ val, const int* __restrict__ rank,
                         const int* __restrict__ row_ptr, int E,
                         int2* __restrict__ csr) {
    int i = blockIdx.x * blockDim.x + threadIdx.x;
    if (i < E) {
        int p = row_ptr[row[i]] + rank[i];
        csr[p] = make_int2(col[i], __float_as_int(val[i]));
    }
}

__device__ __forceinline__ void fma4(float o[4], float sv, const float4& wv) {
    o[0] = fmaf(sv, wv.x, o[0]);
    o[1] = fmaf(sv, wv.y, o[1]);
    o[2] = fmaf(sv, wv.z, o[2]);
    o[3] = fmaf(sv, wv.w, o[3]);
}

// Fused GNN layer. Block = 256 thr (4 waves), 8 nodes per wave, bf16x2
// half-wave pairing.
// R11 phase-1b: 2-stream ping-pong over pair groups. Each of the two streams
// (node-pairs A,B) owns a uint w[8] chunk buffer (8-elem arrays PROVEN to
// SROA-promote: R4/R7 VGPR 28-32 no scratch; 32-elem arrays PROVEN to spill:
// R9/R10). Schedule per chunk: consume A (B's loads in flight) -> reissue A
// -> consume B (A's loads in flight) -> reissue B. Outstanding gathers/wave
// 8 -> 16, consumes execute under the opposite stream's latency. Chunks are
// branch-free (vals zero-masked beyond degree; dead slots read row 0, L1-hot)
// so w[] writes stay unconditional/static. sched_barrier(0) between groups
// blocks cross-group load hoisting (suspected cause of R10's 128-live-reg
// spill). KILL-SIGNAL: FETCH>110MB or WRITE>55MB per layer means spill.
template<int DOUT>
__global__ __launch_bounds__(256, 6) void gnn_layer(
    const float* __restrict__ featsU, const float* __restrict__ featsE, int NUo,
    const __hip_bfloat16* __restrict__ featsb,
    const int2* __restrict__ csr, const int* __restrict__ row_ptr,
    const float* __restrict__ W1, const float* __restrict__ b1,
    const float* __restrict__ W2, const float* __restrict__ b2,
    float* __restrict__ out, __hip_bfloat16* __restrict__ outb, int N) {
    __shared__ __align__(16) float S[32 * 132];
    int wv = threadIdx.x >> 6, lane = threadIdx.x & 63;
    int nb = blockIdx.x * 32 + wv * 8;  // first node of this wave
    int sl = lane & 31;                 // lane within half-wave
    int selbase = lane & 32;            // shfl source base for my half

    // one coalesced row_ptr load -> wave-uniform e0/deg for all 8 nodes (SGPRs)
    int rp_l = row_ptr[min(nb + min(lane, 8), N)];
    int e0[8], dg[8];
#pragma unroll
    for (int ni = 0; ni < 8; ni++) {
        int a = __builtin_amdgcn_readlane(rp_l, ni);
        int b = __builtin_amdgcn_readlane(rp_l, ni + 1);
        e0[ni] = a; dg[ni] = b - a;
    }

    const uint* fb2 = (const uint*)featsb;      // bf16x2 per lane
    const float2* f2u = (const float2*)featsU;
    const float2* f2e = (const float2*)featsE;

    // ---- phase 1a: ONE round of independent metadata + x loads (4 pairs) ----
    int2 m0[4];
    float2 xv[4];
#pragma unroll
    for (int pr = 0; pr < 4; pr++) {
        int idx = 2 * pr + (selbase ? 1 : 0);
        int myDg = dg[idx], myE0 = e0[idx];
        m0[pr] = make_int2(0, 0);
        if (sl < min(myDg, 32)) m0[pr] = csr[myE0 + sl];
        int nn = min(nb + idx, N - 1);
        xv[pr] = (nn < NUo) ? f2u[(size_t)nn * 32 + sl]
                            : f2e[(size_t)(nn - NUo) * 32 + sl];
    }

    // ---- phase 1b: 2-stream ping-pong over pair groups ----
#pragma unroll
    for (int g = 0; g < 2; g++) {
        int pA = 2 * g, pB = 2 * g + 1;
        int idxA = 2 * pA + (selbase ? 1 : 0);
        int idxB = 2 * pB + (selbase ? 1 : 0);
        float axA = 0.f, ayA = 0.f, axB = 0.f, ayB = 0.f;
        uint wA[8], wB[8];
        // prologue: chunk 0 of both streams in flight
#pragma unroll
        for (int u = 0; u < 8; u++)
            wA[u] = fb2[(size_t)__shfl(m0[pA].x, selbase + u, 64) * 32 + sl];
#pragma unroll
        for (int u = 0; u < 8; u++)
            wB[u] = fb2[(size_t)__shfl(m0[pB].x, selbase + u, 64) * 32 + sl];
#pragma unroll
        for (int c = 0; c < 4; c++) {
            // consume A chunk c (B's chunk c still in flight)
#pragma unroll
            for (int u = 0; u < 8; u++) {
                float vv = __int_as_float(__shfl(m0[pA].y, selbase + c * 8 + u, 64));
                axA = fmaf(vv, __uint_as_float(wA[u] << 16), axA);
                ayA = fmaf(vv, __uint_as_float(wA[u] & 0xffff0000u), ayA);
            }
            if (c < 3) {  // reissue A chunk c+1 into the same 8 regs
#pragma unroll
                for (int u = 0; u < 8; u++)
                    wA[u] = fb2[(size_t)__shfl(m0[pA].x, selbase + (c + 1) * 8 + u, 64) * 32 + sl];
            }
            // consume B chunk c (A's chunk c+1 in flight)
#pragma unroll
            for (int u = 0; u < 8; u++) {
                float vv = __int_as_float(__shfl(m0[pB].y, selbase + c * 8 + u, 64));
                axB = fmaf(vv, __uint_as_float(wB[u] << 16), axB);
                ayB = fmaf(vv, __uint_as_float(wB[u] & 0xffff0000u), ayB);
            }
            if (c < 3) {  // reissue B chunk c+1
#pragma unroll
                for (int u = 0; u < 8; u++)
                    wB[u] = fb2[(size_t)__shfl(m0[pB].x, selbase + (c + 1) * 8 + u, 64) * 32 + sl];
            }
        }
        // cold tails: degree > 32 (Poisson(16): ~1e-4 of nodes)
#pragma unroll
        for (int s2 = 0; s2 < 2; s2++) {
            int pr  = s2 ? pB : pA;
            int idx = s2 ? idxB : idxA;
            int myDg = dg[idx], myE0 = e0[idx];
            int mx = max(dg[2 * pr], dg[2 * pr + 1]);    // wave-uniform
            if (mx > 32) {
                float tx = 0.f, ty = 0.f;
                for (int done = 32; done < mx; done += 32) {
                    int2 mt = make_int2(0, 0);
                    if (sl < myDg - done) mt = csr[myE0 + done + sl];
                    int lim2 = min(mx - done, 32);
                    for (int c = 0; c < lim2; c += 8) {
                        uint wt[8]; float vt[8];
#pragma unroll
                        for (int u = 0; u < 8; u++) {
                            int j = c + u;
                            int col = __shfl(mt.x, selbase + j, 64);
                            vt[u] = __int_as_float(__shfl(mt.y, selbase + j, 64));
                            wt[u] = fb2[(size_t)col * 32 + sl];
                        }
#pragma unroll
                        for (int u = 0; u < 8; u++) {
                            tx = fmaf(vt[u], __uint_as_float(wt[u] << 16), tx);
                            ty = fmaf(vt[u], __uint_as_float(wt[u] & 0xffff0000u), ty);
                        }
                    }
                }
                if (s2) { axB += tx; ayB += ty; } else { axA += tx; ayA += ty; }
            }
        }
        // stores
        if (nb + idxA < N) {
            float* sp = &S[(wv * 8 + idxA) * 132];
            *(float2*)&sp[2 * sl]      = make_float2(xv[pA].x + axA, xv[pA].y + ayA);
            *(float2*)&sp[64 + 2 * sl] = make_float2(xv[pA].x * axA, xv[pA].y * ayA);
        }
        if (nb + idxB < N) {
            float* sp = &S[(wv * 8 + idxB) * 132];
            *(float2*)&sp[2 * sl]      = make_float2(xv[pB].x + axB, xv[pB].y + ayB);
            *(float2*)&sp[64 + 2 * sl] = make_float2(xv[pB].x * axB, xv[pB].y * ayB);
        }
        __builtin_amdgcn_sched_barrier(0);  // keep groups' load batches apart
    }
    __threadfence_block();  // wave-local LDS write -> cross-lane read ordering

    // ---- phase 2: MLP + epilogue ----
    if constexpr (DOUT == 64) {
        int strip = lane & 15, g = lane >> 4;    // 16 strips x 4 dims; 4 node-pairs
        int d0 = strip * 4;
        float4 b1v = *(const float4*)&b1[d0];
        float4 b2v = *(const float4*)&b2[d0];
        float oa[4] = {b1v.x + b2v.x, b1v.y + b2v.y, b1v.z + b2v.z, b1v.w + b2v.w};
        float ob[4] = {oa[0], oa[1], oa[2], oa[3]};
        const float* spa = &S[(wv * 8 + 2 * g) * 132];
        const float* spb = spa + 132;
#pragma unroll
        for (int half = 0; half < 2; half++) {
            const float* W  = half ? W2 : W1;
            const float* sa = spa + half * 64;
            const float* sb = spb + half * 64;
#pragma unroll 2
            for (int k = 0; k < 64; k += 4) {
                float4 va = *(const float4*)&sa[k];
                float4 vb = *(const float4*)&sb[k];
                float4 wr0 = *(const float4*)&W[(k + 0) * 64 + d0];
                float4 wr1 = *(const float4*)&W[(k + 1) * 64 + d0];
                float4 wr2 = *(const float4*)&W[(k + 2) * 64 + d0];
                float4 wr3 = *(const float4*)&W[(k + 3) * 64 + d0];
                fma4(oa, va.x, wr0); fma4(oa, va.y, wr1);
                fma4(oa, va.z, wr2); fma4(oa, va.w, wr3);
                fma4(ob, vb.x, wr0); fma4(ob, vb.y, wr1);
                fma4(ob, vb.z, wr2); fma4(ob, vb.w, wr3);
            }
        }
#pragma unroll
        for (int t = 0; t < 2; t++) {
            float* o = t ? ob : oa;
            float h0 = (o[0] > 0.f) ? o[0] : LEAKY * o[0];
            float h1 = (o[1] > 0.f) ? o[1] : LEAKY * o[1];
            float h2 = (o[2] > 0.f) ? o[2] : LEAKY * o[2];
            float h3 = (o[3] > 0.f) ? o[3] : LEAKY * o[3];
            float ss = h0 * h0 + h1 * h1 + h2 * h2 + h3 * h3;
            ss += __shfl_xor(ss, 1, 64);
            ss += __shfl_xor(ss, 2, 64);
            ss += __shfl_xor(ss, 4, 64);
            ss += __shfl_xor(ss, 8, 64);   // 16 lanes = one node
            float sc = 1.0f / fmaxf(sqrtf(ss), 1e-12f);
            int node = nb + 2 * g + t;
            if (node < N) {
                float4 r = {h0 * sc, h1 * sc, h2 * sc, h3 * sc};
                *(float4*)&out[(size_t)node * 64 + d0] = r;
                Bf4 q = {__float2bfloat16(r.x), __float2bfloat16(r.y),
                         __float2bfloat16(r.z), __float2bfloat16(r.w)};
                *(Bf4*)&outb[(size_t)node * 64 + d0] = q;
            }
        }
    } else {
        int strip = lane & 7, nI = lane >> 3;    // 8 strips x 4 dims; 8 nodes
        int d0 = strip * 4;
        float4 b1v = *(const float4*)&b1[d0];
        float4 b2v = *(const float4*)&b2[d0];
        float o[4] = {b1v.x + b2v.x, b1v.y + b2v.y, b1v.z + b2v.z, b1v.w + b2v.w};
        const float* sp = &S[(wv * 8 + nI) * 132];
#pragma unroll
        for (int half = 0; half < 2; half++) {
            const float* W  = half ? W2 : W1;
            const float* sv = sp + half * 64;
#pragma unroll 2
            for (int k = 0; k < 64; k += 4) {
                float4 v   = *(const float4*)&sv[k];
                float4 wr0 = *(const float4*)&W[(k + 0) * 32 + d0];
                float4 wr1 = *(const float4*)&W[(k + 1) * 32 + d0];
                float4 wr2 = *(const float4*)&W[(k + 2) * 32 + d0];
                float4 wr3 = *(const float4*)&W[(k + 3) * 32 + d0];
                fma4(o, v.x, wr0); fma4(o, v.y, wr1);
                fma4(o, v.z, wr2); fma4(o, v.w, wr3);
            }
        }
        float h0 = (o[0] > 0.f) ? o[0] : LEAKY * o[0];
        float h1 = (o[1] > 0.f) ? o[1] : LEAKY * o[1];
        float h2 = (o[2] > 0.f) ? o[2] : LEAKY * o[2];
        float h3 = (o[3] > 0.f) ? o[3] : LEAKY * o[3];
        float ss = h0 * h0 + h1 * h1 + h2 * h2 + h3 * h3;
        ss += __shfl_xor(ss, 1, 64);
        ss += __shfl_xor(ss, 2, 64);
        ss += __shfl_xor(ss, 4, 64);       // 8 lanes = one node
        float sc = 1.0f / fmaxf(sqrtf(ss), 1e-12f);
        int node = nb + nI;
        if (node < N) {
            float4 r = {h0 * sc, h1 * sc, h2 * sc, h3 * sc};
            *(float4*)&out[(size_t)node * 32 + d0] = r;
        }
    }
}

// final = concat(a0, a1, a2); score[b] = dot(final[u], final[NU+i]) over 160
// dims. a0 rows come straight from ue/ee (user row: ue[u]; item row: ee[it]).
__global__ __launch_bounds__(256) void score_pairs(
    const float* __restrict__ ue, const float* __restrict__ ee,
    const float* __restrict__ a1, const float* __restrict__ a2,
    const int* __restrict__ uid, const int* __restrict__ iid,
    float* __restrict__ out, int B, int NU) {
    int wave = threadIdx.x >> 6, lane = threadIdx.x & 63;
    int p = blockIdx.x * 4 + wave;
    if (p >= B) return;
    int u = uid[p], it = iid[p];
    size_t un = (size_t)u, in = (size_t)(NU + it);
    float s = ue[un * 64 + lane] * ee[(size_t)it * 64 + lane];
    s = fmaf(a1[un * 64 + lane], a1[in * 64 + lane], s);
    if (lane < 32) s = fmaf(a2[un * 32 + lane], a2[in * 32 + lane], s);
#pragma unroll
    for (int m = 32; m >= 1; m >>= 1) s += __shfl_xor(s, m, 64);
    if (lane == 0) out[p] = s;
}

extern "C" void kernel_launch(void* const* d_in, const int* in_sizes, int n_in,
                              void* d_out, int out_size, void* d_ws, size_t ws_size,
                              hipStream_t stream) {
    const int*   edge_row  = (const int*)d_in[0];
    const int*   edge_col  = (const int*)d_in[1];
    const float* edge_vals = (const float*)d_in[2];
    const float* ue        = (const float*)d_in[3];
    const float* ee        = (const float*)d_in[4];
    const float* W1_0 = (const float*)d_in[5];
    const float* b1_0 = (const float*)d_in[6];
    const float* W2_0 = (const float*)d_in[7];
    const float* b2_0 = (const float*)d_in[8];
    const float* W1_1 = (const float*)d_in[9];
    const float* b1_1 = (const float*)d_in[10];
    const float* W2_1 = (const float*)d_in[11];
    const float* b2_1 = (const float*)d_in[12];
    const int*   uid  = (const int*)d_in[13];
    const int*   iid  = (const int*)d_in[14];
    float* out = (float*)d_out;

    const int E  = in_sizes[0];
    const int NU = in_sizes[3] / 64;
    const int NE = in_sizes[4] / 64;
    const int N  = NU + NE;
    const int B  = in_sizes[13];
    const int G  = (N + SCAN_TILE - 1) / SCAN_TILE;

    char* ws = (char*)d_ws;
    size_t off = 0;
    auto alloc = [&](size_t bytes) -> char* {
        char* p = ws + off;
        off = (off + bytes + 255) & ~(size_t)255;
        return p;
    };
    int*   deg      = (int*)alloc((size_t)N * 4);
    int*   rank     = (int*)alloc((size_t)E * 4);
    int*   row_ptr  = (int*)alloc((size_t)(N + 1) * 4);
    int*   blocksum = (int*)alloc((size_t)1024 * 4);
    int2*  csr      = (int2*)alloc((size_t)E * 8);
    float* a1       = (float*)alloc((size_t)N * 64 * 4);
    float* a2       = (float*)alloc((size_t)N * 32 * 4);
    __hip_bfloat16* a0b = (__hip_bfloat16*)alloc((size_t)N * 64 * 2);
    __hip_bfloat16* a1b = (__hip_bfloat16*)alloc((size_t)N * 64 * 2);
    (void)ws_size; (void)n_in; (void)out_size; (void)NE;

    int ntot4 = N * 16, nu4 = NU * 16;
    int prepN = max(E, ntot4);

    hipMemsetAsync(deg, 0, (size_t)N * 4, stream);
    prep<<<(prepN + 255) / 256, 256, 0, stream>>>(edge_row, E, deg, rank,
                                                  (const float4*)ue, (const float4*)ee,
                                                  a0b, nu4, ntot4);
    scan_phase1<<<G, SCAN_BLOCK, 0, stream>>>(deg, blocksum, N);
    scan_phase23<<<G, SCAN_BLOCK, 0, stream>>>(deg, blocksum, row_ptr, N);
    fill_csr<<<(E + 255) / 256, 256, 0, stream>>>(edge_row, edge_col, edge_vals,
                                                  rank, row_ptr, E, csr);
    gnn_layer<64><<<(N + 31) / 32, 256, 0, stream>>>(ue, ee, NU, a0b, csr, row_ptr,
                                                     W1_0, b1_0, W2_0, b2_0, a1, a1b, N);
    gnn_layer<32><<<(N + 31) / 32, 256, 0, stream>>>(a1, a1, N, a1b, csr, row_ptr,
                                                     W1_1, b1_1, W2_1, b2_1, a2, nullptr, N);
    score_pairs<<<(B + 3) / 4, 256, 0, stream>>>(ue, ee, a1, a2, uid, iid, out, B, NU);
}

// Round 12
// 369.600 us; speedup vs baseline: 1.6331x; 1.6331x over previous
//
#include <hip/hip_runtime.h>
#include <hip/hip_bf16.h>
#include <math.h>

#define LEAKY 0.01f
#define SCAN_BLOCK 256
#define SCAN_ITEMS 4
#define SCAN_TILE (SCAN_BLOCK * SCAN_ITEMS)  // 1024 items per block

struct __align__(8) Bf4 { __hip_bfloat16 a, b, c, d; };

// prep: degree histogram WITH returned rank (returning atomic lives in its
// own streaming kernel, overlapped across the grid) fused with the bf16
// conversion of concat(ue, ee).
__global__ void prep(const int* __restrict__ row, int E,
                     int* __restrict__ deg, int* __restrict__ rank,
                     const float4* __restrict__ ue, const float4* __restrict__ ee,
                     __hip_bfloat16* __restrict__ a0b, int nu4, int ntot4) {
    int i = blockIdx.x * blockDim.x + threadIdx.x;
    if (i < E) rank[i] = atomicAdd(&deg[row[i]], 1);
    if (i < ntot4) {
        float4 v = (i < nu4) ? ue[i] : ee[i - nu4];
        Bf4 q = {__float2bfloat16(v.x), __float2bfloat16(v.y),
                 __float2bfloat16(v.z), __float2bfloat16(v.w)};
        *(Bf4*)&a0b[(size_t)i * 4] = q;
    }
}

// ---- scan of deg[N] -> row_ptr[N+1], 2 dispatches ----
__global__ __launch_bounds__(SCAN_BLOCK) void scan_phase1(
    const int* __restrict__ deg, int* __restrict__ blocksum, int N) {
    __shared__ int red[SCAN_BLOCK];
    int b = blockIdx.x, t = threadIdx.x;
    int base = b * SCAN_TILE + t * SCAN_ITEMS;
    int s = 0;
#pragma unroll
    for (int j = 0; j < SCAN_ITEMS; j++) {
        int i = base + j;
        if (i < N) s += deg[i];
    }
    red[t] = s;
    __syncthreads();
    for (int off = SCAN_BLOCK / 2; off > 0; off >>= 1) {
        if (t < off) red[t] += red[t + off];
        __syncthreads();
    }
    if (t == 0) blocksum[b] = red[0];
}

// fused phase2+phase3: every block recomputes its own offset from blocksum
// (G<=1024 ints, L2-broadcast, ~free). row_ptr[N] by thread i==N-1.
__global__ __launch_bounds__(SCAN_BLOCK) void scan_phase23(
    const int* __restrict__ deg, const int* __restrict__ blocksum,
    int* __restrict__ row_ptr, int N) {
    __shared__ int red[SCAN_BLOCK];
    __shared__ int boff_s;
    int b = blockIdx.x, t = threadIdx.x;
    int part = 0;
    for (int j = t; j < b; j += SCAN_BLOCK) part += blocksum[j];
    red[t] = part;
    __syncthreads();
    for (int off = SCAN_BLOCK / 2; off > 0; off >>= 1) {
        if (t < off) red[t] += red[t + off];
        __syncthreads();
    }
    if (t == 0) boff_s = red[0];
    __syncthreads();
    int base = b * SCAN_TILE + t * SCAN_ITEMS;
    int v[SCAN_ITEMS];
    int s = 0;
#pragma unroll
    for (int j = 0; j < SCAN_ITEMS; j++) {
        int i = base + j;
        v[j] = (i < N) ? deg[i] : 0;
        s += v[j];
    }
    red[t] = s;
    __syncthreads();
    for (int off = 1; off < SCAN_BLOCK; off <<= 1) {
        int x = (t >= off) ? red[t - off] : 0;
        __syncthreads();
        red[t] += x;
        __syncthreads();
    }
    int run = boff_s + ((t == 0) ? 0 : red[t - 1]);
#pragma unroll
    for (int j = 0; j < SCAN_ITEMS; j++) {
        int i = base + j;
        if (i < N) {
            row_ptr[i] = run;
            run += v[j];
            if (i == N - 1) row_ptr[N] = run;
        }
    }
}
// ----------------------------------------------------------------------

// atomic-free CSR fill using precomputed ranks (pure read -> gather ->
// scatter, no atomic in the dependency chain).
__global__ void fill_csr(const int* __restrict__ row, const int* __restrict__ col,
                         const float* __restrict__ val, const int* __restrict__ rank,
                         const int* __restrict__ row_ptr, int E,
                         int2* __restrict__ csr) {
    int i = blockIdx.x * blockDim.x + threadIdx.x;
    if (i < E) {
        int p = row_ptr[row[i]] + rank[i];
        csr[p] = make_int2(col[i], __float_as_int(val[i]));
    }
}

__device__ __forceinline__ void fma4(float o[4], float sv, const float4& wv) {
    o[0] = fmaf(sv, wv.x, o[0]);
    o[1] = fmaf(sv, wv.y, o[1]);
    o[2] = fmaf(sv, wv.z, o[2]);
    o[3] = fmaf(sv, wv.w, o[3]);
}

// Fused GNN layer — R7 verified-best structure (370.5 us total).
// Block = 256 thr (4 waves), 8 nodes per wave, bf16x2 half-wave pairing:
// 32 lanes cover a 64-dim row as ushort2; the wave's two halves process two
// nodes concurrently; one shfl per field serves both halves; bf16->f32 via
// shift. 8-element chunk buffers ONLY (proven SROA-promotable; 16+ element
// buffers spill on this backend — R9/R10/R11 all regressed).
template<int DOUT>
__global__ __launch_bounds__(256, 8) void gnn_layer(
    const float* __restrict__ featsU, const float* __restrict__ featsE, int NUo,
    const __hip_bfloat16* __restrict__ featsb,
    const int2* __restrict__ csr, const int* __restrict__ row_ptr,
    const float* __restrict__ W1, const float* __restrict__ b1,
    const float* __restrict__ W2, const float* __restrict__ b2,
    float* __restrict__ out, __hip_bfloat16* __restrict__ outb, int N) {
    __shared__ __align__(16) float S[32 * 132];
    int wv = threadIdx.x >> 6, lane = threadIdx.x & 63;
    int nb = blockIdx.x * 32 + wv * 8;  // first node of this wave
    int sl = lane & 31;                 // lane within half-wave
    int selbase = lane & 32;            // shfl source base for my half

    // one coalesced row_ptr load -> wave-uniform e0/deg for all 8 nodes (SGPRs)
    int rp_l = row_ptr[min(nb + min(lane, 8), N)];
    int e0[8], dg[8];
#pragma unroll
    for (int ni = 0; ni < 8; ni++) {
        int a = __builtin_amdgcn_readlane(rp_l, ni);
        int b = __builtin_amdgcn_readlane(rp_l, ni + 1);
        e0[ni] = a; dg[ni] = b - a;
    }

    const uint* fb2 = (const uint*)featsb;      // bf16x2 per lane
    const float2* f2u = (const float2*)featsU;
    const float2* f2e = (const float2*)featsE;

    // ---- phase 1a: ONE round of independent metadata + x loads (4 pairs) ----
    int2 m0[4];
    float2 xv[4];
#pragma unroll
    for (int pr = 0; pr < 4; pr++) {
        int idx = 2 * pr + (selbase ? 1 : 0);
        int myDg = dg[idx], myE0 = e0[idx];
        m0[pr] = make_int2(0, 0);
        if (sl < min(myDg, 32)) m0[pr] = csr[myE0 + sl];
        int nn = min(nb + idx, N - 1);
        xv[pr] = (nn < NUo) ? f2u[(size_t)nn * 32 + sl]
                            : f2e[(size_t)(nn - NUo) * 32 + sl];
    }

    // ---- phase 1b: consume pairs (gathers of pr+1 overlap fma of pr) ----
#pragma unroll
    for (int pr = 0; pr < 4; pr++) {
        int idx = 2 * pr + (selbase ? 1 : 0);
        int myDg = dg[idx], myE0 = e0[idx];
        int mx = max(dg[2 * pr], dg[2 * pr + 1]);    // wave-uniform
        float accx = 0.f, accy = 0.f;
        int lim = min(mx, 32);
        for (int c = 0; c < lim; c += 8) {
            uint w[8]; float vv[8];
#pragma unroll
            for (int u = 0; u < 8; u++) {
                int j = c + u;
                int col = __shfl(m0[pr].x, selbase + j, 64);
                vv[u] = __int_as_float(__shfl(m0[pr].y, selbase + j, 64));
                w[u] = fb2[(size_t)col * 32 + sl];
            }
#pragma unroll
            for (int u = 0; u < 8; u++) {
                accx = fmaf(vv[u], __uint_as_float(w[u] << 16), accx);
                accy = fmaf(vv[u], __uint_as_float(w[u] & 0xffff0000u), accy);
            }
        }
        if (mx > 32) {  // cold tail: degree > 32
            for (int done = 32; done < mx; done += 32) {
                int2 mt = make_int2(0, 0);
                if (sl < myDg - done) mt = csr[myE0 + done + sl];
                int lim2 = min(mx - done, 32);
                for (int c = 0; c < lim2; c += 8) {
                    uint w[8]; float vv[8];
#pragma unroll
                    for (int u = 0; u < 8; u++) {
                        int j = c + u;
                        int col = __shfl(mt.x, selbase + j, 64);
                        vv[u] = __int_as_float(__shfl(mt.y, selbase + j, 64));
                        w[u] = fb2[(size_t)col * 32 + sl];
                    }
#pragma unroll
                    for (int u = 0; u < 8; u++) {
                        accx = fmaf(vv[u], __uint_as_float(w[u] << 16), accx);
                        accy = fmaf(vv[u], __uint_as_float(w[u] & 0xffff0000u), accy);
                    }
                }
            }
        }
        if (nb + idx < N) {
            float* sp = &S[(wv * 8 + idx) * 132];
            *(float2*)&sp[2 * sl]      = make_float2(xv[pr].x + accx, xv[pr].y + accy);  // s1
            *(float2*)&sp[64 + 2 * sl] = make_float2(xv[pr].x * accx, xv[pr].y * accy);  // s2
        }
    }
    __threadfence_block();  // wave-local LDS write -> cross-lane read ordering

    // ---- phase 2: MLP + epilogue ----
    if constexpr (DOUT == 64) {
        int strip = lane & 15, g = lane >> 4;    // 16 strips x 4 dims; 4 node-pairs
        int d0 = strip * 4;
        float4 b1v = *(const float4*)&b1[d0];
        float4 b2v = *(const float4*)&b2[d0];
        float oa[4] = {b1v.x + b2v.x, b1v.y + b2v.y, b1v.z + b2v.z, b1v.w + b2v.w};
        float ob[4] = {oa[0], oa[1], oa[2], oa[3]};
        const float* spa = &S[(wv * 8 + 2 * g) * 132];
        const float* spb = spa + 132;
#pragma unroll
        for (int half = 0; half < 2; half++) {
            const float* W  = half ? W2 : W1;
            const float* sa = spa + half * 64;
            const float* sb = spb + half * 64;
#pragma unroll 2
            for (int k = 0; k < 64; k += 4) {
                float4 va = *(const float4*)&sa[k];
                float4 vb = *(const float4*)&sb[k];
                float4 wr0 = *(const float4*)&W[(k + 0) * 64 + d0];
                float4 wr1 = *(const float4*)&W[(k + 1) * 64 + d0];
                float4 wr2 = *(const float4*)&W[(k + 2) * 64 + d0];
                float4 wr3 = *(const float4*)&W[(k + 3) * 64 + d0];
                fma4(oa, va.x, wr0); fma4(oa, va.y, wr1);
                fma4(oa, va.z, wr2); fma4(oa, va.w, wr3);
                fma4(ob, vb.x, wr0); fma4(ob, vb.y, wr1);
                fma4(ob, vb.z, wr2); fma4(ob, vb.w, wr3);
            }
        }
#pragma unroll
        for (int t = 0; t < 2; t++) {
            float* o = t ? ob : oa;
            float h0 = (o[0] > 0.f) ? o[0] : LEAKY * o[0];
            float h1 = (o[1] > 0.f) ? o[1] : LEAKY * o[1];
            float h2 = (o[2] > 0.f) ? o[2] : LEAKY * o[2];
            float h3 = (o[3] > 0.f) ? o[3] : LEAKY * o[3];
            float ss = h0 * h0 + h1 * h1 + h2 * h2 + h3 * h3;
            ss += __shfl_xor(ss, 1, 64);
            ss += __shfl_xor(ss, 2, 64);
            ss += __shfl_xor(ss, 4, 64);
            ss += __shfl_xor(ss, 8, 64);   // 16 lanes = one node
            float sc = 1.0f / fmaxf(sqrtf(ss), 1e-12f);
            int node = nb + 2 * g + t;
            if (node < N) {
                float4 r = {h0 * sc, h1 * sc, h2 * sc, h3 * sc};
                *(float4*)&out[(size_t)node * 64 + d0] = r;
                Bf4 q = {__float2bfloat16(r.x), __float2bfloat16(r.y),
                         __float2bfloat16(r.z), __float2bfloat16(r.w)};
                *(Bf4*)&outb[(size_t)node * 64 + d0] = q;
            }
        }
    } else {
        int strip = lane & 7, nI = lane >> 3;    // 8 strips x 4 dims; 8 nodes
        int d0 = strip * 4;
        float4 b1v = *(const float4*)&b1[d0];
        float4 b2v = *(const float4*)&b2[d0];
        float o[4] = {b1v.x + b2v.x, b1v.y + b2v.y, b1v.z + b2v.z, b1v.w + b2v.w};
        const float* sp = &S[(wv * 8 + nI) * 132];
#pragma unroll
        for (int half = 0; half < 2; half++) {
            const float* W  = half ? W2 : W1;
            const float* sv = sp + half * 64;
#pragma unroll 2
            for (int k = 0; k < 64; k += 4) {
                float4 v   = *(const float4*)&sv[k];
                float4 wr0 = *(const float4*)&W[(k + 0) * 32 + d0];
                float4 wr1 = *(const float4*)&W[(k + 1) * 32 + d0];
                float4 wr2 = *(const float4*)&W[(k + 2) * 32 + d0];
                float4 wr3 = *(const float4*)&W[(k + 3) * 32 + d0];
                fma4(o, v.x, wr0); fma4(o, v.y, wr1);
                fma4(o, v.z, wr2); fma4(o, v.w, wr3);
            }
        }
        float h0 = (o[0] > 0.f) ? o[0] : LEAKY * o[0];
        float h1 = (o[1] > 0.f) ? o[1] : LEAKY * o[1];
        float h2 = (o[2] > 0.f) ? o[2] : LEAKY * o[2];
        float h3 = (o[3] > 0.f) ? o[3] : LEAKY * o[3];
        float ss = h0 * h0 + h1 * h1 + h2 * h2 + h3 * h3;
        ss += __shfl_xor(ss, 1, 64);
        ss += __shfl_xor(ss, 2, 64);
        ss += __shfl_xor(ss, 4, 64);       // 8 lanes = one node
        float sc = 1.0f / fmaxf(sqrtf(ss), 1e-12f);
        int node = nb + nI;
        if (node < N) {
            float4 r = {h0 * sc, h1 * sc, h2 * sc, h3 * sc};
            *(float4*)&out[(size_t)node * 32 + d0] = r;
        }
    }
}

// final = concat(a0, a1, a2); score[b] = dot(final[u], final[NU+i]) over 160
// dims. a0 rows come straight from ue/ee (user row: ue[u]; item row: ee[it]).
__global__ __launch_bounds__(256) void score_pairs(
    const float* __restrict__ ue, const float* __restrict__ ee,
    const float* __restrict__ a1, const float* __restrict__ a2,
    const int* __restrict__ uid, const int* __restrict__ iid,
    float* __restrict__ out, int B, int NU) {
    int wave = threadIdx.x >> 6, lane = threadIdx.x & 63;
    int p = blockIdx.x * 4 + wave;
    if (p >= B) return;
    int u = uid[p], it = iid[p];
    size_t un = (size_t)u, in = (size_t)(NU + it);
    float s = ue[un * 64 + lane] * ee[(size_t)it * 64 + lane];
    s = fmaf(a1[un * 64 + lane], a1[in * 64 + lane], s);
    if (lane < 32) s = fmaf(a2[un * 32 + lane], a2[in * 32 + lane], s);
#pragma unroll
    for (int m = 32; m >= 1; m >>= 1) s += __shfl_xor(s, m, 64);
    if (lane == 0) out[p] = s;
}

extern "C" void kernel_launch(void* const* d_in, const int* in_sizes, int n_in,
                              void* d_out, int out_size, void* d_ws, size_t ws_size,
                              hipStream_t stream) {
    const int*   edge_row  = (const int*)d_in[0];
    const int*   edge_col  = (const int*)d_in[1];
    const float* edge_vals = (const float*)d_in[2];
    const float* ue        = (const float*)d_in[3];
    const float* ee        = (const float*)d_in[4];
    const float* W1_0 = (const float*)d_in[5];
    const float* b1_0 = (const float*)d_in[6];
    const float* W2_0 = (const float*)d_in[7];
    const float* b2_0 = (const float*)d_in[8];
    const float* W1_1 = (const float*)d_in[9];
    const float* b1_1 = (const float*)d_in[10];
    const float* W2_1 = (const float*)d_in[11];
    const float* b2_1 = (const float*)d_in[12];
    const int*   uid  = (const int*)d_in[13];
    const int*   iid  = (const int*)d_in[14];
    float* out = (float*)d_out;

    const int E  = in_sizes[0];
    const int NU = in_sizes[3] / 64;
    const int NE = in_sizes[4] / 64;
    const int N  = NU + NE;
    const int B  = in_sizes[13];
    const int G  = (N + SCAN_TILE - 1) / SCAN_TILE;

    char* ws = (char*)d_ws;
    size_t off = 0;
    auto alloc = [&](size_t bytes) -> char* {
        char* p = ws + off;
        off = (off + bytes + 255) & ~(size_t)255;
        return p;
    };
    int*   deg      = (int*)alloc((size_t)N * 4);
    int*   rank     = (int*)alloc((size_t)E * 4);
    int*   row_ptr  = (int*)alloc((size_t)(N + 1) * 4);
    int*   blocksum = (int*)alloc((size_t)1024 * 4);
    int2*  csr      = (int2*)alloc((size_t)E * 8);
    float* a1       = (float*)alloc((size_t)N * 64 * 4);
    float* a2       = (float*)alloc((size_t)N * 32 * 4);
    __hip_bfloat16* a0b = (__hip_bfloat16*)alloc((size_t)N * 64 * 2);
    __hip_bfloat16* a1b = (__hip_bfloat16*)alloc((size_t)N * 64 * 2);
    (void)ws_size; (void)n_in; (void)out_size; (void)NE;

    int ntot4 = N * 16, nu4 = NU * 16;
    int prepN = max(E, ntot4);

    hipMemsetAsync(deg, 0, (size_t)N * 4, stream);
    prep<<<(prepN + 255) / 256, 256, 0, stream>>>(edge_row, E, deg, rank,
                                                  (const float4*)ue, (const float4*)ee,
                                                  a0b, nu4, ntot4);
    scan_phase1<<<G, SCAN_BLOCK, 0, stream>>>(deg, blocksum, N);
    scan_phase23<<<G, SCAN_BLOCK, 0, stream>>>(deg, blocksum, row_ptr, N);
    fill_csr<<<(E + 255) / 256, 256, 0, stream>>>(edge_row, edge_col, edge_vals,
                                                  rank, row_ptr, E, csr);
    gnn_layer<64><<<(N + 31) / 32, 256, 0, stream>>>(ue, ee, NU, a0b, csr, row_ptr,
                                                     W1_0, b1_0, W2_0, b2_0, a1, a1b, N);
    gnn_layer<32><<<(N + 31) / 32, 256, 0, stream>>>(a1, a1, N, a1b, csr, row_ptr,
                                                     W1_1, b1_1, W2_1, b2_1, a2, nullptr, N);
    score_pairs<<<(B + 3) / 4, 256, 0, stream>>>(ue, ee, a1, a2, uid, iid, out, B, NU);
}